// Round 4
// baseline (283.187 us; speedup 1.0000x reference)
//
#include <hip/hip_runtime.h>

typedef __attribute__((ext_vector_type(4))) short short4v;
typedef __attribute__((ext_vector_type(8))) short short8;
typedef __attribute__((ext_vector_type(4))) float f32x4;

#define NWIN 4096

__device__ __forceinline__ short f2bf(float f) {
    unsigned int u = __builtin_bit_cast(unsigned int, f);
    u += 0x7fffu + ((u >> 16) & 1u);
    return (short)(u >> 16);
}

// proven pack: low half = a, high half = b
__device__ __forceinline__ unsigned pack2(float a, float b) {
    return (unsigned)(unsigned short)f2bf(a) | ((unsigned)(unsigned short)f2bf(b) << 16);
}

__device__ __forceinline__ short4v pk4(float a, float b, float c, float d) {
    uint2 u;
    u.x = pack2(a, b);
    u.y = pack2(c, d);
    return __builtin_bit_cast(short4v, u);
}

#define LOG2E 1.4426950408889634f
#define QSCALE 0.17677669529663687f  // 32^-0.5

// ---- prep: transpose weights to bf16 (q-scale & log2e folded), permuted bias ----
__global__ void prep_kernel(const float* __restrict__ w_qkv,
                            const float* __restrict__ w_out,
                            const float* __restrict__ bias_table,
                            short* __restrict__ wqkvT,   // [384][128] bf16
                            short* __restrict__ woutT,   // [128][128] bf16
                            float* __restrict__ biasP)   // [4][4][64][16] f32, *log2e
{
    int id = blockIdx.x * 256 + threadIdx.x;
    if (id < 49152) {
        int j = id >> 7, k = id & 127;
        float v = w_qkv[k * 384 + j];
        if (j < 128) v *= (QSCALE * LOG2E);   // fold attention scale + log2e into Wq
        wqkvT[id] = f2bf(v);
    } else if (id < 65536) {
        int t = id - 49152;
        int j = t >> 7, k = t & 127;
        woutT[t] = f2bf(w_out[k * 128 + j]);
    } else if (id < 81920) {
        int t = id - 65536;
        // layout: [h][ib][ln][jb*4+r]; lane ln=(g<<4)|lo holds (i=16ib+lo, j=16jb+4g+r)
        int m  = t & 15;
        int ln = (t >> 4) & 63;
        int ib = (t >> 10) & 3;
        int h  = t >> 12;
        int lo = ln & 15, g = ln >> 4;
        int i = ib * 16 + lo;
        int j = (m >> 2) * 16 + g * 4 + (m & 3);
        int ri = i >> 3, ci = i & 7, rj = j >> 3, cj = j & 7;
        int idx = (ri - rj + 7) * 15 + (ci - cj + 7);
        biasP[t] = bias_table[idx * 4 + h] * LOG2E;
    }
}

// ---- fused: LN -> QKV -> attention(+bias, softmax) -> out proj ----
__global__ __launch_bounds__(256, 4)
void attn_kernel(const float* __restrict__ x,
                 const float* __restrict__ gamma,
                 const float* __restrict__ beta,
                 const short* __restrict__ wqkvT,
                 const short* __restrict__ woutT,
                 const float* __restrict__ biasP,
                 float* __restrict__ out)
{
    // LDS map (32 KiB):
    //   [0,16K)   XN [64][128] bf16 (swz); after b2 reused as AO (same layout)
    //   [16K + h*4K): vT [32][64] bf16 per head (wave-private)
    __shared__ __align__(16) char smem[32768];

    const int tid = threadIdx.x;
    const int h  = tid >> 6;
    const int ln = tid & 63;
    const int lo = ln & 15, g = ln >> 4;

    const float* xwin = x + (size_t)blockIdx.x * 8192;

    // ---------------- LayerNorm -> XN (16 lanes/row, 8 ch/lane) ----------------
    float4 va[4][2];
    #pragma unroll
    for (int p = 0; p < 4; ++p) {
        int t = h * 16 + p * 4 + g;
        const float4* xr = (const float4*)(xwin + t * 128 + lo * 8);
        va[p][0] = xr[0];
        va[p][1] = xr[1];
    }
    float4 ga0 = ((const float4*)gamma)[lo * 2], ga1 = ((const float4*)gamma)[lo * 2 + 1];
    float4 be0 = ((const float4*)beta)[lo * 2],  be1 = ((const float4*)beta)[lo * 2 + 1];

    #pragma unroll
    for (int p = 0; p < 4; ++p) {
        int t = h * 16 + p * 4 + g;
        float4 v0 = va[p][0], v1 = va[p][1];
        float s  = v0.x + v0.y + v0.z + v0.w + v1.x + v1.y + v1.z + v1.w;
        float sq = v0.x*v0.x + v0.y*v0.y + v0.z*v0.z + v0.w*v0.w
                 + v1.x*v1.x + v1.y*v1.y + v1.z*v1.z + v1.w*v1.w;
        #pragma unroll
        for (int m = 1; m < 16; m <<= 1) {
            s  += __shfl_xor(s, m, 64);
            sq += __shfl_xor(sq, m, 64);
        }
        float mu  = s * (1.f / 128.f);
        float var = sq * (1.f / 128.f) - mu * mu;
        float rs  = rsqrtf(var + 1e-5f);
        float y0 = (v0.x - mu) * rs * ga0.x + be0.x;
        float y1 = (v0.y - mu) * rs * ga0.y + be0.y;
        float y2 = (v0.z - mu) * rs * ga0.z + be0.z;
        float y3 = (v0.w - mu) * rs * ga0.w + be0.w;
        float y4 = (v1.x - mu) * rs * ga1.x + be1.x;
        float y5 = (v1.y - mu) * rs * ga1.y + be1.y;
        float y6 = (v1.z - mu) * rs * ga1.z + be1.z;
        float y7 = (v1.w - mu) * rs * ga1.w + be1.w;
        uint4 pk;
        pk.x = pack2(y0, y1); pk.y = pack2(y2, y3);
        pk.z = pack2(y4, y5); pk.w = pack2(y6, y7);
        *(uint4*)(smem + ((t * 256 + lo * 16) ^ ((t & 7) << 4))) = pk;
    }
    __syncthreads();  // b1: XN ready

    const f32x4 z4 = {0.f, 0.f, 0.f, 0.f};

    // ---------------- QKV phase 1: Q,K (swapped: mfma(w, xn) -> D[c][t]) ----------------
    f32x4 qt[2][4], kt[2][4];
    #pragma unroll
    for (int a = 0; a < 2; ++a)
        #pragma unroll
        for (int b = 0; b < 4; ++b) { qt[a][b] = z4; kt[a][b] = z4; }

    #pragma unroll
    for (int kk = 0; kk < 4; ++kk) {
        short8 xa[4];
        #pragma unroll
        for (int tb = 0; tb < 4; ++tb) {
            int t = tb * 16 + lo;
            xa[tb] = *(const short8*)(smem + ((t * 256 + kk * 64 + g * 16) ^ ((t & 7) << 4)));
        }
        #pragma unroll
        for (int cb = 0; cb < 2; ++cb) {
            short8 wqf = *(const short8*)(wqkvT + (      h * 32 + cb * 16 + lo) * 128 + kk * 32 + g * 8);
            short8 wkf = *(const short8*)(wqkvT + (128 + h * 32 + cb * 16 + lo) * 128 + kk * 32 + g * 8);
            #pragma unroll
            for (int tb = 0; tb < 4; ++tb) {
                qt[cb][tb] = __builtin_amdgcn_mfma_f32_16x16x32_bf16(wqf, xa[tb], qt[cb][tb], 0, 0, 0);
                kt[cb][tb] = __builtin_amdgcn_mfma_f32_16x16x32_bf16(wkf, xa[tb], kt[cb][tb], 0, 0, 0);
            }
        }
    }

    // pack Q,K accumulators straight into 16x16x16 fragments (k = 4g+e matches reg r!)
    short4v kA[2][4], qB[2][4];   // [ck][jb] / [ck][ib]
    #pragma unroll
    for (int ck = 0; ck < 2; ++ck)
        #pragma unroll
        for (int tb = 0; tb < 4; ++tb) {
            kA[ck][tb] = pk4(kt[ck][tb][0], kt[ck][tb][1], kt[ck][tb][2], kt[ck][tb][3]);
            qB[ck][tb] = pk4(qt[ck][tb][0], qt[ck][tb][1], qt[ck][tb][2], qt[ck][tb][3]);
        }

    // ---------------- QKV phase 2: V (normal: mfma(xn, w) -> D[t][c]) ----------------
    f32x4 vv[4][2];
    #pragma unroll
    for (int a = 0; a < 4; ++a)
        #pragma unroll
        for (int b = 0; b < 2; ++b) vv[a][b] = z4;

    #pragma unroll
    for (int kk = 0; kk < 4; ++kk) {
        short8 xa[4];
        #pragma unroll
        for (int tb = 0; tb < 4; ++tb) {
            int t = tb * 16 + lo;
            xa[tb] = *(const short8*)(smem + ((t * 256 + kk * 64 + g * 16) ^ ((t & 7) << 4)));
        }
        #pragma unroll
        for (int cb = 0; cb < 2; ++cb) {
            short8 wvf = *(const short8*)(wqkvT + (256 + h * 32 + cb * 16 + lo) * 128 + kk * 32 + g * 8);
            #pragma unroll
            for (int tb = 0; tb < 4; ++tb)
                vv[tb][cb] = __builtin_amdgcn_mfma_f32_16x16x32_bf16(xa[tb], wvf, vv[tb][cb], 0, 0, 0);
        }
    }

    // vT LDS [c][t] rows (wave-private region; no barrier needed)
    char* vtb = smem + 16384 + h * 4096;
    #pragma unroll
    for (int cb = 0; cb < 2; ++cb)
        #pragma unroll
        for (int tb = 0; tb < 4; ++tb) {
            int c = cb * 16 + lo;
            uint2 w;
            w.x = pack2(vv[tb][cb][0], vv[tb][cb][1]);
            w.y = pack2(vv[tb][cb][2], vv[tb][cb][3]);
            *(uint2*)(vtb + ((c * 128 + tb * 32 + g * 8) ^ ((c & 7) << 4))) = w;
        }

    // bias prefetch for ib=0
    f32x4 bias_cur[4], bias_nxt[4];
    {
        const f32x4* bp = (const f32x4*)(biasP + ((h * 4 + 0) * 64 + ln) * 16);
        #pragma unroll
        for (int jb = 0; jb < 4; ++jb) bias_cur[jb] = bp[jb];
    }

    // ---------------- QK^T (16x16x16 from registers; S^T = K . Q^T) ----------------
    f32x4 st[4][4];  // [ib][jb]: lane holds i=16ib+lo, j=16jb+4g+r
    #pragma unroll
    for (int a = 0; a < 4; ++a)
        #pragma unroll
        for (int b = 0; b < 4; ++b) st[a][b] = z4;

    #pragma unroll
    for (int ib = 0; ib < 4; ++ib)
        #pragma unroll
        for (int jb = 0; jb < 4; ++jb) {
            st[ib][jb] = __builtin_amdgcn_mfma_f32_16x16x16bf16_1k(kA[0][jb], qB[0][ib], st[ib][jb], 0, 0, 0);
            st[ib][jb] = __builtin_amdgcn_mfma_f32_16x16x16bf16_1k(kA[1][jb], qB[1][ib], st[ib][jb], 0, 0, 0);
        }

    // ---------------- softmax (in-lane 16 + shfl 16/32); P stays in registers ----------------
    short4v pB[4][4];  // [ib][jk] PV B-fragments
    float inv[4];
    #pragma unroll
    for (int ib = 0; ib < 4; ++ib) {
        if (ib < 3) {
            const f32x4* bp = (const f32x4*)(biasP + ((h * 4 + ib + 1) * 64 + ln) * 16);
            #pragma unroll
            for (int jb = 0; jb < 4; ++jb) bias_nxt[jb] = bp[jb];
        }
        float v[16];
        #pragma unroll
        for (int jb = 0; jb < 4; ++jb)
            #pragma unroll
            for (int r = 0; r < 4; ++r)
                v[jb * 4 + r] = st[ib][jb][r] + bias_cur[jb][r];
        float mx = v[0];
        #pragma unroll
        for (int q = 1; q < 16; ++q) mx = fmaxf(mx, v[q]);
        mx = fmaxf(mx, __shfl_xor(mx, 16, 64));
        mx = fmaxf(mx, __shfl_xor(mx, 32, 64));
        float s = 0.f;
        #pragma unroll
        for (int q = 0; q < 16; ++q) { v[q] = __builtin_exp2f(v[q] - mx); s += v[q]; }
        s += __shfl_xor(s, 16, 64);
        s += __shfl_xor(s, 32, 64);
        inv[ib] = 1.f / s;
        #pragma unroll
        for (int jk = 0; jk < 4; ++jk)
            pB[ib][jk] = pk4(v[jk * 4 + 0], v[jk * 4 + 1], v[jk * 4 + 2], v[jk * 4 + 3]);
        #pragma unroll
        for (int jb = 0; jb < 4; ++jb) bias_cur[jb] = bias_nxt[jb];
    }

    // ---------------- PV (16x16x16: O^T = V^T . P^T; A from vT LDS, B from regs) ----------------
    f32x4 ot[2][4];  // [cb][ib]
    #pragma unroll
    for (int a = 0; a < 2; ++a)
        #pragma unroll
        for (int b = 0; b < 4; ++b) ot[a][b] = z4;

    #pragma unroll
    for (int jk = 0; jk < 4; ++jk)
        #pragma unroll
        for (int cb = 0; cb < 2; ++cb) {
            int c = cb * 16 + lo;
            short4v vA = __builtin_bit_cast(short4v,
                *(const uint2*)(vtb + ((c * 128 + jk * 32 + g * 8) ^ ((c & 7) << 4))));
            #pragma unroll
            for (int ib = 0; ib < 4; ++ib)
                ot[cb][ib] = __builtin_amdgcn_mfma_f32_16x16x16bf16_1k(vA, pB[ib][jk], ot[cb][ib], 0, 0, 0);
        }
    __syncthreads();  // b2: all waves past QKV (XN reads done) -> AO may overlay [0,16K)

    #pragma unroll
    for (int cb = 0; cb < 2; ++cb)
        #pragma unroll
        for (int ib = 0; ib < 4; ++ib) {
            int i = ib * 16 + lo;
            float sc = inv[ib];
            uint2 w;
            w.x = pack2(ot[cb][ib][0] * sc, ot[cb][ib][1] * sc);
            w.y = pack2(ot[cb][ib][2] * sc, ot[cb][ib][3] * sc);
            *(uint2*)(smem + ((i * 256 + (h * 32 + cb * 16 + g * 4) * 2) ^ ((i & 7) << 4))) = w;
        }
    __syncthreads();  // b3: AO ready

    // ---------------- out projection (swapped: out^T = Wout^T . AO^T, 16x16x32) ----------------
    f32x4 ft[2][4];  // [cj][tb]
    #pragma unroll
    for (int a = 0; a < 2; ++a)
        #pragma unroll
        for (int b = 0; b < 4; ++b) ft[a][b] = z4;

    #pragma unroll
    for (int kk = 0; kk < 4; ++kk) {
        short8 ao[4];
        #pragma unroll
        for (int tb = 0; tb < 4; ++tb) {
            int t = tb * 16 + lo;
            ao[tb] = *(const short8*)(smem + ((t * 256 + kk * 64 + g * 16) ^ ((t & 7) << 4)));
        }
        #pragma unroll
        for (int cj = 0; cj < 2; ++cj) {
            short8 wof = *(const short8*)(woutT + (h * 32 + cj * 16 + lo) * 128 + kk * 32 + g * 8);
            #pragma unroll
            for (int tb = 0; tb < 4; ++tb)
                ft[cj][tb] = __builtin_amdgcn_mfma_f32_16x16x32_bf16(wof, ao[tb], ft[cj][tb], 0, 0, 0);
        }
    }

    float* owin = out + (size_t)blockIdx.x * 8192;
    #pragma unroll
    for (int cj = 0; cj < 2; ++cj)
        #pragma unroll
        for (int tb = 0; tb < 4; ++tb) {
            int t = tb * 16 + lo;
            *(f32x4*)(owin + t * 128 + h * 32 + cj * 16 + g * 4) = ft[cj][tb];
        }
}

extern "C" void kernel_launch(void* const* d_in, const int* in_sizes, int n_in,
                              void* d_out, int out_size, void* d_ws, size_t ws_size,
                              hipStream_t stream) {
    const float* x          = (const float*)d_in[0];
    const float* gamma      = (const float*)d_in[1];
    const float* beta       = (const float*)d_in[2];
    const float* w_qkv      = (const float*)d_in[3];
    const float* w_out      = (const float*)d_in[4];
    const float* bias_table = (const float*)d_in[5];

    short* wqkvT = (short*)d_ws;                    // 98304 B
    short* woutT = (short*)((char*)d_ws + 98304);   // 32768 B
    float* biasP = (float*)((char*)d_ws + 131072);  // 65536 B

    prep_kernel<<<320, 256, 0, stream>>>(w_qkv, w_out, bias_table, wqkvT, woutT, biasP);
    attn_kernel<<<NWIN, 256, 0, stream>>>(x, gamma, beta, wqkvT, woutT, biasP, (float*)d_out);
}

// Round 5
// 277.254 us; speedup vs baseline: 1.0214x; 1.0214x over previous
//
#include <hip/hip_runtime.h>

typedef __attribute__((ext_vector_type(4))) short short4v;
typedef __attribute__((ext_vector_type(8))) short short8;
typedef __attribute__((ext_vector_type(4))) float f32x4;

#define NWIN 4096

__device__ __forceinline__ short f2bf(float f) {
    unsigned int u = __builtin_bit_cast(unsigned int, f);
    u += 0x7fffu + ((u >> 16) & 1u);
    return (short)(u >> 16);
}

// proven pack: low half = a, high half = b
__device__ __forceinline__ unsigned pack2(float a, float b) {
    return (unsigned)(unsigned short)f2bf(a) | ((unsigned)(unsigned short)f2bf(b) << 16);
}

__device__ __forceinline__ short4v pk4(float a, float b, float c, float d) {
    uint2 u;
    u.x = pack2(a, b);
    u.y = pack2(c, d);
    return __builtin_bit_cast(short4v, u);
}

#define LOG2E 1.4426950408889634f
#define QSCALE 0.17677669529663687f  // 32^-0.5

// ---- prep: transpose weights to bf16 (q-scale & log2e folded), permuted bias ----
__global__ void prep_kernel(const float* __restrict__ w_qkv,
                            const float* __restrict__ w_out,
                            const float* __restrict__ bias_table,
                            short* __restrict__ wqkvT,   // [384][128] bf16
                            short* __restrict__ woutT,   // [128][128] bf16
                            float* __restrict__ biasP)   // [4][4][64][16] f32, *log2e
{
    int id = blockIdx.x * 256 + threadIdx.x;
    if (id < 49152) {
        int j = id >> 7, k = id & 127;
        float v = w_qkv[k * 384 + j];
        if (j < 128) v *= (QSCALE * LOG2E);   // fold attention scale + log2e into Wq
        wqkvT[id] = f2bf(v);
    } else if (id < 65536) {
        int t = id - 49152;
        int j = t >> 7, k = t & 127;
        woutT[t] = f2bf(w_out[k * 128 + j]);
    } else if (id < 81920) {
        int t = id - 65536;
        // layout: [h][ib][ln][jb*4+r]; lane ln=(g<<4)|lo holds (i=16ib+lo, j=16jb+4g+r)
        int m  = t & 15;
        int ln = (t >> 4) & 63;
        int ib = (t >> 10) & 3;
        int h  = t >> 12;
        int lo = ln & 15, g = ln >> 4;
        int i = ib * 16 + lo;
        int j = (m >> 2) * 16 + g * 4 + (m & 3);
        int ri = i >> 3, ci = i & 7, rj = j >> 3, cj = j & 7;
        int idx = (ri - rj + 7) * 15 + (ci - cj + 7);
        biasP[t] = bias_table[idx * 4 + h] * LOG2E;
    }
}

// ---- fused: LN -> QKV -> attention(+bias, softmax) -> out proj ----
__global__ __launch_bounds__(256)
__attribute__((amdgpu_waves_per_eu(4, 4)))
void attn_kernel(const float* __restrict__ x,
                 const float* __restrict__ gamma,
                 const float* __restrict__ beta,
                 const short* __restrict__ wqkvT,
                 const short* __restrict__ woutT,
                 const float* __restrict__ biasP,
                 float* __restrict__ out)
{
    // LDS map (32 KiB):
    //   [0,16K)   XN [64][128] bf16 (swz); after b2 reused as AO (same layout)
    //   [16K + h*4K): vT [32][64] bf16 per head (wave-private)
    __shared__ __align__(16) char smem[32768];

    const int tid = threadIdx.x;
    const int h  = tid >> 6;
    const int ln = tid & 63;
    const int lo = ln & 15, g = ln >> 4;

    const float* xwin = x + (size_t)blockIdx.x * 8192;

    // ---------------- LayerNorm -> XN (16 lanes/row, 8 ch/lane) ----------------
    float4 va[4][2];
    #pragma unroll
    for (int p = 0; p < 4; ++p) {
        int t = h * 16 + p * 4 + g;
        const float4* xr = (const float4*)(xwin + t * 128 + lo * 8);
        va[p][0] = xr[0];
        va[p][1] = xr[1];
    }
    float4 ga0 = ((const float4*)gamma)[lo * 2], ga1 = ((const float4*)gamma)[lo * 2 + 1];
    float4 be0 = ((const float4*)beta)[lo * 2],  be1 = ((const float4*)beta)[lo * 2 + 1];

    #pragma unroll
    for (int p = 0; p < 4; ++p) {
        int t = h * 16 + p * 4 + g;
        float4 v0 = va[p][0], v1 = va[p][1];
        float s  = v0.x + v0.y + v0.z + v0.w + v1.x + v1.y + v1.z + v1.w;
        float sq = v0.x*v0.x + v0.y*v0.y + v0.z*v0.z + v0.w*v0.w
                 + v1.x*v1.x + v1.y*v1.y + v1.z*v1.z + v1.w*v1.w;
        #pragma unroll
        for (int m = 1; m < 16; m <<= 1) {
            s  += __shfl_xor(s, m, 64);
            sq += __shfl_xor(sq, m, 64);
        }
        float mu  = s * (1.f / 128.f);
        float var = sq * (1.f / 128.f) - mu * mu;
        float rs  = rsqrtf(var + 1e-5f);
        float y0 = (v0.x - mu) * rs * ga0.x + be0.x;
        float y1 = (v0.y - mu) * rs * ga0.y + be0.y;
        float y2 = (v0.z - mu) * rs * ga0.z + be0.z;
        float y3 = (v0.w - mu) * rs * ga0.w + be0.w;
        float y4 = (v1.x - mu) * rs * ga1.x + be1.x;
        float y5 = (v1.y - mu) * rs * ga1.y + be1.y;
        float y6 = (v1.z - mu) * rs * ga1.z + be1.z;
        float y7 = (v1.w - mu) * rs * ga1.w + be1.w;
        uint4 pk;
        pk.x = pack2(y0, y1); pk.y = pack2(y2, y3);
        pk.z = pack2(y4, y5); pk.w = pack2(y6, y7);
        *(uint4*)(smem + ((t * 256 + lo * 16) ^ ((t & 7) << 4))) = pk;
    }
    __syncthreads();  // b1: XN ready

    const f32x4 z4 = {0.f, 0.f, 0.f, 0.f};

    // ---------------- QKV phase 1: Q,K (swapped: mfma(w, xn) -> D[c][t]) ----------------
    f32x4 qt[2][4], kt[2][4];
    #pragma unroll
    for (int a = 0; a < 2; ++a)
        #pragma unroll
        for (int b = 0; b < 4; ++b) { qt[a][b] = z4; kt[a][b] = z4; }

    #pragma unroll
    for (int kk = 0; kk < 4; ++kk) {
        short8 xa[4];
        #pragma unroll
        for (int tb = 0; tb < 4; ++tb) {
            int t = tb * 16 + lo;
            xa[tb] = *(const short8*)(smem + ((t * 256 + kk * 64 + g * 16) ^ ((t & 7) << 4)));
        }
        #pragma unroll
        for (int cb = 0; cb < 2; ++cb) {
            short8 wqf = *(const short8*)(wqkvT + (      h * 32 + cb * 16 + lo) * 128 + kk * 32 + g * 8);
            short8 wkf = *(const short8*)(wqkvT + (128 + h * 32 + cb * 16 + lo) * 128 + kk * 32 + g * 8);
            #pragma unroll
            for (int tb = 0; tb < 4; ++tb) {
                qt[cb][tb] = __builtin_amdgcn_mfma_f32_16x16x32_bf16(wqf, xa[tb], qt[cb][tb], 0, 0, 0);
                kt[cb][tb] = __builtin_amdgcn_mfma_f32_16x16x32_bf16(wkf, xa[tb], kt[cb][tb], 0, 0, 0);
            }
        }
    }

    // pack Q,K accumulators straight into 16x16x16 fragments (k = 4g+e matches reg r!)
    short4v kA[2][4], qB[2][4];   // [ck][jb] / [ck][ib]
    #pragma unroll
    for (int ck = 0; ck < 2; ++ck)
        #pragma unroll
        for (int tb = 0; tb < 4; ++tb) {
            kA[ck][tb] = pk4(kt[ck][tb][0], kt[ck][tb][1], kt[ck][tb][2], kt[ck][tb][3]);
            qB[ck][tb] = pk4(qt[ck][tb][0], qt[ck][tb][1], qt[ck][tb][2], qt[ck][tb][3]);
        }

    // ---------------- QKV phase 2: V (normal: mfma(xn, w) -> D[t][c]) ----------------
    f32x4 vv[4][2];
    #pragma unroll
    for (int a = 0; a < 4; ++a)
        #pragma unroll
        for (int b = 0; b < 2; ++b) vv[a][b] = z4;

    #pragma unroll
    for (int kk = 0; kk < 4; ++kk) {
        short8 xa[4];
        #pragma unroll
        for (int tb = 0; tb < 4; ++tb) {
            int t = tb * 16 + lo;
            xa[tb] = *(const short8*)(smem + ((t * 256 + kk * 64 + g * 16) ^ ((t & 7) << 4)));
        }
        #pragma unroll
        for (int cb = 0; cb < 2; ++cb) {
            short8 wvf = *(const short8*)(wqkvT + (256 + h * 32 + cb * 16 + lo) * 128 + kk * 32 + g * 8);
            #pragma unroll
            for (int tb = 0; tb < 4; ++tb)
                vv[tb][cb] = __builtin_amdgcn_mfma_f32_16x16x32_bf16(xa[tb], wvf, vv[tb][cb], 0, 0, 0);
        }
    }

    // vT LDS [c][t] rows (wave-private region; no barrier needed)
    char* vtb = smem + 16384 + h * 4096;
    #pragma unroll
    for (int cb = 0; cb < 2; ++cb)
        #pragma unroll
        for (int tb = 0; tb < 4; ++tb) {
            int c = cb * 16 + lo;
            uint2 w;
            w.x = pack2(vv[tb][cb][0], vv[tb][cb][1]);
            w.y = pack2(vv[tb][cb][2], vv[tb][cb][3]);
            *(uint2*)(vtb + ((c * 128 + tb * 32 + g * 8) ^ ((c & 7) << 4))) = w;
        }

    // ---------------- per-ib fused: QK^T (x16, regs) -> softmax -> PV (x16) ----------------
    f32x4 ot[2][4];  // [cb][ib]
    #pragma unroll
    for (int a = 0; a < 2; ++a)
        #pragma unroll
        for (int b = 0; b < 4; ++b) ot[a][b] = z4;

    float inv[4];
    #pragma unroll
    for (int ib = 0; ib < 4; ++ib) {
        // bias for this ib (L2-resident, coalesced)
        f32x4 bias_cur[4];
        {
            const f32x4* bp = (const f32x4*)(biasP + ((h * 4 + ib) * 64 + ln) * 16);
            #pragma unroll
            for (int jb = 0; jb < 4; ++jb) bias_cur[jb] = bp[jb];
        }

        // QK^T for this ib: S^T = K . Q^T  (lane holds i=16ib+lo, j=16jb+4g+r)
        f32x4 st[4];
        #pragma unroll
        for (int jb = 0; jb < 4; ++jb) st[jb] = z4;
        #pragma unroll
        for (int jb = 0; jb < 4; ++jb) {
            st[jb] = __builtin_amdgcn_mfma_f32_16x16x16bf16_1k(kA[0][jb], qB[0][ib], st[jb], 0, 0, 0);
            st[jb] = __builtin_amdgcn_mfma_f32_16x16x16bf16_1k(kA[1][jb], qB[1][ib], st[jb], 0, 0, 0);
        }

        // softmax (in-lane 16 + shfl 16/32); P stays in registers
        float v[16];
        #pragma unroll
        for (int jb = 0; jb < 4; ++jb)
            #pragma unroll
            for (int r = 0; r < 4; ++r)
                v[jb * 4 + r] = st[jb][r] + bias_cur[jb][r];
        float mx = v[0];
        #pragma unroll
        for (int q = 1; q < 16; ++q) mx = fmaxf(mx, v[q]);
        mx = fmaxf(mx, __shfl_xor(mx, 16, 64));
        mx = fmaxf(mx, __shfl_xor(mx, 32, 64));
        float s = 0.f;
        #pragma unroll
        for (int q = 0; q < 16; ++q) { v[q] = __builtin_exp2f(v[q] - mx); s += v[q]; }
        s += __shfl_xor(s, 16, 64);
        s += __shfl_xor(s, 32, 64);
        inv[ib] = 1.f / s;

        short4v pB[4];
        #pragma unroll
        for (int jk = 0; jk < 4; ++jk)
            pB[jk] = pk4(v[jk * 4 + 0], v[jk * 4 + 1], v[jk * 4 + 2], v[jk * 4 + 3]);

        // PV for this ib: O^T = V^T . P^T  (A from vT LDS, B from regs)
        #pragma unroll
        for (int jk = 0; jk < 4; ++jk)
            #pragma unroll
            for (int cb = 0; cb < 2; ++cb) {
                int c = cb * 16 + lo;
                short4v vA = __builtin_bit_cast(short4v,
                    *(const uint2*)(vtb + ((c * 128 + jk * 32 + g * 8) ^ ((c & 7) << 4))));
                ot[cb][ib] = __builtin_amdgcn_mfma_f32_16x16x16bf16_1k(vA, pB[jk], ot[cb][ib], 0, 0, 0);
            }
    }
    __syncthreads();  // b2: all waves past QKV (XN reads done) -> AO may overlay [0,16K)

    #pragma unroll
    for (int cb = 0; cb < 2; ++cb)
        #pragma unroll
        for (int ib = 0; ib < 4; ++ib) {
            int i = ib * 16 + lo;
            float sc = inv[ib];
            uint2 w;
            w.x = pack2(ot[cb][ib][0] * sc, ot[cb][ib][1] * sc);
            w.y = pack2(ot[cb][ib][2] * sc, ot[cb][ib][3] * sc);
            *(uint2*)(smem + ((i * 256 + (h * 32 + cb * 16 + g * 4) * 2) ^ ((i & 7) << 4))) = w;
        }
    __syncthreads();  // b3: AO ready

    // ---------------- out projection (swapped: out^T = Wout^T . AO^T, 16x16x32) ----------------
    f32x4 ft[2][4];  // [cj][tb]
    #pragma unroll
    for (int a = 0; a < 2; ++a)
        #pragma unroll
        for (int b = 0; b < 4; ++b) ft[a][b] = z4;

    #pragma unroll
    for (int kk = 0; kk < 4; ++kk) {
        short8 ao[4];
        #pragma unroll
        for (int tb = 0; tb < 4; ++tb) {
            int t = tb * 16 + lo;
            ao[tb] = *(const short8*)(smem + ((t * 256 + kk * 64 + g * 16) ^ ((t & 7) << 4)));
        }
        #pragma unroll
        for (int cj = 0; cj < 2; ++cj) {
            short8 wof = *(const short8*)(woutT + (h * 32 + cj * 16 + lo) * 128 + kk * 32 + g * 8);
            #pragma unroll
            for (int tb = 0; tb < 4; ++tb)
                ft[cj][tb] = __builtin_amdgcn_mfma_f32_16x16x32_bf16(wof, ao[tb], ft[cj][tb], 0, 0, 0);
        }
    }

    float* owin = out + (size_t)blockIdx.x * 8192;
    #pragma unroll
    for (int cj = 0; cj < 2; ++cj)
        #pragma unroll
        for (int tb = 0; tb < 4; ++tb) {
            int t = tb * 16 + lo;
            *(f32x4*)(owin + t * 128 + h * 32 + cj * 16 + g * 4) = ft[cj][tb];
        }
}

extern "C" void kernel_launch(void* const* d_in, const int* in_sizes, int n_in,
                              void* d_out, int out_size, void* d_ws, size_t ws_size,
                              hipStream_t stream) {
    const float* x          = (const float*)d_in[0];
    const float* gamma      = (const float*)d_in[1];
    const float* beta       = (const float*)d_in[2];
    const float* w_qkv      = (const float*)d_in[3];
    const float* w_out      = (const float*)d_in[4];
    const float* bias_table = (const float*)d_in[5];

    short* wqkvT = (short*)d_ws;                    // 98304 B
    short* woutT = (short*)((char*)d_ws + 98304);   // 32768 B
    float* biasP = (float*)((char*)d_ws + 131072);  // 65536 B

    prep_kernel<<<320, 256, 0, stream>>>(w_qkv, w_out, bias_table, wqkvT, woutT, biasP);
    attn_kernel<<<NWIN, 256, 0, stream>>>(x, gamma, beta, wqkvT, woutT, biasP, (float*)d_out);
}

// Round 6
// 132.122 us; speedup vs baseline: 2.1434x; 2.0985x over previous
//
#include <hip/hip_runtime.h>

typedef __attribute__((ext_vector_type(4))) short short4v;
typedef __attribute__((ext_vector_type(8))) short short8;
typedef __attribute__((ext_vector_type(4))) float f32x4;

#define NWIN 4096

__device__ __forceinline__ short f2bf(float f) {
    unsigned int u = __builtin_bit_cast(unsigned int, f);
    u += 0x7fffu + ((u >> 16) & 1u);
    return (short)(u >> 16);
}

// proven pack: low half = a, high half = b
__device__ __forceinline__ unsigned pack2(float a, float b) {
    return (unsigned)(unsigned short)f2bf(a) | ((unsigned)(unsigned short)f2bf(b) << 16);
}

__device__ __forceinline__ short4v pk4(float a, float b, float c, float d) {
    uint2 u;
    u.x = pack2(a, b);
    u.y = pack2(c, d);
    return __builtin_bit_cast(short4v, u);
}

#define LOG2E 1.4426950408889634f
#define QSCALE 0.17677669529663687f  // 32^-0.5

// ---- prep: transpose weights to bf16 (q-scale & log2e folded), permuted bias ----
__global__ void prep_kernel(const float* __restrict__ w_qkv,
                            const float* __restrict__ w_out,
                            const float* __restrict__ bias_table,
                            short* __restrict__ wqkvT,   // [384][128] bf16
                            short* __restrict__ woutT,   // [128][128] bf16
                            float* __restrict__ biasP)   // [4][4][64][16] f32, *log2e
{
    int id = blockIdx.x * 256 + threadIdx.x;
    if (id < 49152) {
        int j = id >> 7, k = id & 127;
        float v = w_qkv[k * 384 + j];
        if (j < 128) v *= (QSCALE * LOG2E);   // fold attention scale + log2e into Wq
        wqkvT[id] = f2bf(v);
    } else if (id < 65536) {
        int t = id - 49152;
        int j = t >> 7, k = t & 127;
        woutT[t] = f2bf(w_out[k * 128 + j]);
    } else if (id < 81920) {
        int t = id - 65536;
        // layout: [h][ib][ln][jb*4+r]; lane ln=(g<<4)|lo holds (i=16ib+lo, j=16jb+4g+r)
        int m  = t & 15;
        int ln = (t >> 4) & 63;
        int ib = (t >> 10) & 3;
        int h  = t >> 12;
        int lo = ln & 15, g = ln >> 4;
        int i = ib * 16 + lo;
        int j = (m >> 2) * 16 + g * 4 + (m & 3);
        int ri = i >> 3, ci = i & 7, rj = j >> 3, cj = j & 7;
        int idx = (ri - rj + 7) * 15 + (ci - cj + 7);
        biasP[t] = bias_table[idx * 4 + h] * LOG2E;
    }
}

// ---- fused: LN -> QKV -> attention(+bias, softmax) -> out proj ----
__global__ __launch_bounds__(256, 2)
void attn_kernel(const float* __restrict__ x,
                 const float* __restrict__ gamma,
                 const float* __restrict__ beta,
                 const short* __restrict__ wqkvT,
                 const short* __restrict__ woutT,
                 const float* __restrict__ biasP,
                 float* __restrict__ out)
{
    // LDS map (32 KiB):
    //   [0,16K)   XN [64][128] bf16 (swz); after b2 reused as AO (same layout)
    //   [16K + h*4K): vT [32][64] bf16 per head (wave-private)
    __shared__ __align__(16) char smem[32768];

    const int tid = threadIdx.x;
    const int h  = tid >> 6;
    const int ln = tid & 63;
    const int lo = ln & 15, g = ln >> 4;

    const float* xwin = x + (size_t)blockIdx.x * 8192;

    // ---------------- LayerNorm -> XN (16 lanes/row, 8 ch/lane) ----------------
    float4 va[4][2];
    #pragma unroll
    for (int p = 0; p < 4; ++p) {
        int t = h * 16 + p * 4 + g;
        const float4* xr = (const float4*)(xwin + t * 128 + lo * 8);
        va[p][0] = xr[0];
        va[p][1] = xr[1];
    }
    float4 ga0 = ((const float4*)gamma)[lo * 2], ga1 = ((const float4*)gamma)[lo * 2 + 1];
    float4 be0 = ((const float4*)beta)[lo * 2],  be1 = ((const float4*)beta)[lo * 2 + 1];

    #pragma unroll
    for (int p = 0; p < 4; ++p) {
        int t = h * 16 + p * 4 + g;
        float4 v0 = va[p][0], v1 = va[p][1];
        float s  = v0.x + v0.y + v0.z + v0.w + v1.x + v1.y + v1.z + v1.w;
        float sq = v0.x*v0.x + v0.y*v0.y + v0.z*v0.z + v0.w*v0.w
                 + v1.x*v1.x + v1.y*v1.y + v1.z*v1.z + v1.w*v1.w;
        #pragma unroll
        for (int m = 1; m < 16; m <<= 1) {
            s  += __shfl_xor(s, m, 64);
            sq += __shfl_xor(sq, m, 64);
        }
        float mu  = s * (1.f / 128.f);
        float var = sq * (1.f / 128.f) - mu * mu;
        float rs  = rsqrtf(var + 1e-5f);
        float y0 = (v0.x - mu) * rs * ga0.x + be0.x;
        float y1 = (v0.y - mu) * rs * ga0.y + be0.y;
        float y2 = (v0.z - mu) * rs * ga0.z + be0.z;
        float y3 = (v0.w - mu) * rs * ga0.w + be0.w;
        float y4 = (v1.x - mu) * rs * ga1.x + be1.x;
        float y5 = (v1.y - mu) * rs * ga1.y + be1.y;
        float y6 = (v1.z - mu) * rs * ga1.z + be1.z;
        float y7 = (v1.w - mu) * rs * ga1.w + be1.w;
        uint4 pk;
        pk.x = pack2(y0, y1); pk.y = pack2(y2, y3);
        pk.z = pack2(y4, y5); pk.w = pack2(y6, y7);
        *(uint4*)(smem + ((t * 256 + lo * 16) ^ ((t & 7) << 4))) = pk;
    }
    __syncthreads();  // b1: XN ready

    const f32x4 z4 = {0.f, 0.f, 0.f, 0.f};

    // ---------------- QKV phase 1: Q,K (swapped: mfma(w, xn) -> D[c][t]) ----------------
    f32x4 qt[2][4], kt[2][4];
    #pragma unroll
    for (int a = 0; a < 2; ++a)
        #pragma unroll
        for (int b = 0; b < 4; ++b) { qt[a][b] = z4; kt[a][b] = z4; }

    #pragma unroll
    for (int kk = 0; kk < 4; ++kk) {
        short8 xa[4];
        #pragma unroll
        for (int tb = 0; tb < 4; ++tb) {
            int t = tb * 16 + lo;
            xa[tb] = *(const short8*)(smem + ((t * 256 + kk * 64 + g * 16) ^ ((t & 7) << 4)));
        }
        #pragma unroll
        for (int cb = 0; cb < 2; ++cb) {
            short8 wqf = *(const short8*)(wqkvT + (      h * 32 + cb * 16 + lo) * 128 + kk * 32 + g * 8);
            short8 wkf = *(const short8*)(wqkvT + (128 + h * 32 + cb * 16 + lo) * 128 + kk * 32 + g * 8);
            #pragma unroll
            for (int tb = 0; tb < 4; ++tb) {
                qt[cb][tb] = __builtin_amdgcn_mfma_f32_16x16x32_bf16(wqf, xa[tb], qt[cb][tb], 0, 0, 0);
                kt[cb][tb] = __builtin_amdgcn_mfma_f32_16x16x32_bf16(wkf, xa[tb], kt[cb][tb], 0, 0, 0);
            }
        }
    }

    // pack Q,K accumulators straight into 16x16x16 fragments (k = 4g+e matches reg r!)
    short4v kA[2][4], qB[2][4];   // [ck][jb] / [ck][ib]
    #pragma unroll
    for (int ck = 0; ck < 2; ++ck)
        #pragma unroll
        for (int tb = 0; tb < 4; ++tb) {
            kA[ck][tb] = pk4(kt[ck][tb][0], kt[ck][tb][1], kt[ck][tb][2], kt[ck][tb][3]);
            qB[ck][tb] = pk4(qt[ck][tb][0], qt[ck][tb][1], qt[ck][tb][2], qt[ck][tb][3]);
        }

    // ---------------- QKV phase 2: V (normal: mfma(xn, w) -> D[t][c]) ----------------
    f32x4 vv[4][2];
    #pragma unroll
    for (int a = 0; a < 4; ++a)
        #pragma unroll
        for (int b = 0; b < 2; ++b) vv[a][b] = z4;

    #pragma unroll
    for (int kk = 0; kk < 4; ++kk) {
        short8 xa[4];
        #pragma unroll
        for (int tb = 0; tb < 4; ++tb) {
            int t = tb * 16 + lo;
            xa[tb] = *(const short8*)(smem + ((t * 256 + kk * 64 + g * 16) ^ ((t & 7) << 4)));
        }
        #pragma unroll
        for (int cb = 0; cb < 2; ++cb) {
            short8 wvf = *(const short8*)(wqkvT + (256 + h * 32 + cb * 16 + lo) * 128 + kk * 32 + g * 8);
            #pragma unroll
            for (int tb = 0; tb < 4; ++tb)
                vv[tb][cb] = __builtin_amdgcn_mfma_f32_16x16x32_bf16(xa[tb], wvf, vv[tb][cb], 0, 0, 0);
        }
    }

    // vT LDS [c][t] rows (wave-private region; no barrier needed)
    char* vtb = smem + 16384 + h * 4096;
    #pragma unroll
    for (int cb = 0; cb < 2; ++cb)
        #pragma unroll
        for (int tb = 0; tb < 4; ++tb) {
            int c = cb * 16 + lo;
            uint2 w;
            w.x = pack2(vv[tb][cb][0], vv[tb][cb][1]);
            w.y = pack2(vv[tb][cb][2], vv[tb][cb][3]);
            *(uint2*)(vtb + ((c * 128 + tb * 32 + g * 8) ^ ((c & 7) << 4))) = w;
        }

    // ---------------- per-ib fused: QK^T (x16, regs) -> softmax -> PV (x16) ----------------
    f32x4 ot[2][4];  // [cb][ib]
    #pragma unroll
    for (int a = 0; a < 2; ++a)
        #pragma unroll
        for (int b = 0; b < 4; ++b) ot[a][b] = z4;

    float inv[4];
    #pragma unroll
    for (int ib = 0; ib < 4; ++ib) {
        // bias for this ib (L2-resident, coalesced)
        f32x4 bias_cur[4];
        {
            const f32x4* bp = (const f32x4*)(biasP + ((h * 4 + ib) * 64 + ln) * 16);
            #pragma unroll
            for (int jb = 0; jb < 4; ++jb) bias_cur[jb] = bp[jb];
        }

        // QK^T for this ib: S^T = K . Q^T  (lane holds i=16ib+lo, j=16jb+4g+r)
        f32x4 st[4];
        #pragma unroll
        for (int jb = 0; jb < 4; ++jb) st[jb] = z4;
        #pragma unroll
        for (int jb = 0; jb < 4; ++jb) {
            st[jb] = __builtin_amdgcn_mfma_f32_16x16x16bf16_1k(kA[0][jb], qB[0][ib], st[jb], 0, 0, 0);
            st[jb] = __builtin_amdgcn_mfma_f32_16x16x16bf16_1k(kA[1][jb], qB[1][ib], st[jb], 0, 0, 0);
        }

        // softmax (in-lane 16 + shfl 16/32); P stays in registers
        float v[16];
        #pragma unroll
        for (int jb = 0; jb < 4; ++jb)
            #pragma unroll
            for (int r = 0; r < 4; ++r)
                v[jb * 4 + r] = st[jb][r] + bias_cur[jb][r];
        float mx = v[0];
        #pragma unroll
        for (int q = 1; q < 16; ++q) mx = fmaxf(mx, v[q]);
        mx = fmaxf(mx, __shfl_xor(mx, 16, 64));
        mx = fmaxf(mx, __shfl_xor(mx, 32, 64));
        float s = 0.f;
        #pragma unroll
        for (int q = 0; q < 16; ++q) { v[q] = __builtin_exp2f(v[q] - mx); s += v[q]; }
        s += __shfl_xor(s, 16, 64);
        s += __shfl_xor(s, 32, 64);
        inv[ib] = 1.f / s;

        short4v pB[4];
        #pragma unroll
        for (int jk = 0; jk < 4; ++jk)
            pB[jk] = pk4(v[jk * 4 + 0], v[jk * 4 + 1], v[jk * 4 + 2], v[jk * 4 + 3]);

        // PV for this ib: O^T = V^T . P^T  (A from vT LDS, B from regs)
        #pragma unroll
        for (int jk = 0; jk < 4; ++jk)
            #pragma unroll
            for (int cb = 0; cb < 2; ++cb) {
                int c = cb * 16 + lo;
                short4v vA = __builtin_bit_cast(short4v,
                    *(const uint2*)(vtb + ((c * 128 + jk * 32 + g * 8) ^ ((c & 7) << 4))));
                ot[cb][ib] = __builtin_amdgcn_mfma_f32_16x16x16bf16_1k(vA, pB[jk], ot[cb][ib], 0, 0, 0);
            }
    }
    __syncthreads();  // b2: all waves past QKV (XN reads done) -> AO may overlay [0,16K)

    #pragma unroll
    for (int cb = 0; cb < 2; ++cb)
        #pragma unroll
        for (int ib = 0; ib < 4; ++ib) {
            int i = ib * 16 + lo;
            float sc = inv[ib];
            uint2 w;
            w.x = pack2(ot[cb][ib][0] * sc, ot[cb][ib][1] * sc);
            w.y = pack2(ot[cb][ib][2] * sc, ot[cb][ib][3] * sc);
            *(uint2*)(smem + ((i * 256 + (h * 32 + cb * 16 + g * 4) * 2) ^ ((i & 7) << 4))) = w;
        }
    __syncthreads();  // b3: AO ready

    // ---------------- out projection (swapped: out^T = Wout^T . AO^T, 16x16x32) ----------------
    f32x4 ft[2][4];  // [cj][tb]
    #pragma unroll
    for (int a = 0; a < 2; ++a)
        #pragma unroll
        for (int b = 0; b < 4; ++b) ft[a][b] = z4;

    #pragma unroll
    for (int kk = 0; kk < 4; ++kk) {
        short8 ao[4];
        #pragma unroll
        for (int tb = 0; tb < 4; ++tb) {
            int t = tb * 16 + lo;
            ao[tb] = *(const short8*)(smem + ((t * 256 + kk * 64 + g * 16) ^ ((t & 7) << 4)));
        }
        #pragma unroll
        for (int cj = 0; cj < 2; ++cj) {
            short8 wof = *(const short8*)(woutT + (h * 32 + cj * 16 + lo) * 128 + kk * 32 + g * 8);
            #pragma unroll
            for (int tb = 0; tb < 4; ++tb)
                ft[cj][tb] = __builtin_amdgcn_mfma_f32_16x16x32_bf16(wof, ao[tb], ft[cj][tb], 0, 0, 0);
        }
    }

    float* owin = out + (size_t)blockIdx.x * 8192;
    #pragma unroll
    for (int cj = 0; cj < 2; ++cj)
        #pragma unroll
        for (int tb = 0; tb < 4; ++tb) {
            int t = tb * 16 + lo;
            *(f32x4*)(owin + t * 128 + h * 32 + cj * 16 + g * 4) = ft[cj][tb];
        }
}

extern "C" void kernel_launch(void* const* d_in, const int* in_sizes, int n_in,
                              void* d_out, int out_size, void* d_ws, size_t ws_size,
                              hipStream_t stream) {
    const float* x          = (const float*)d_in[0];
    const float* gamma      = (const float*)d_in[1];
    const float* beta       = (const float*)d_in[2];
    const float* w_qkv      = (const float*)d_in[3];
    const float* w_out      = (const float*)d_in[4];
    const float* bias_table = (const float*)d_in[5];

    short* wqkvT = (short*)d_ws;                    // 98304 B
    short* woutT = (short*)((char*)d_ws + 98304);   // 32768 B
    float* biasP = (float*)((char*)d_ws + 131072);  // 65536 B

    prep_kernel<<<320, 256, 0, stream>>>(w_qkv, w_out, bias_table, wqkvT, woutT, biasP);
    attn_kernel<<<NWIN, 256, 0, stream>>>(x, gamma, beta, wqkvT, woutT, biasP, (float*)d_out);
}